// Round 8
// baseline (186.955 us; speedup 1.0000x reference)
//
#include <hip/hip_runtime.h>
#include <hip/hip_bf16.h>

// Problem constants
#define H 1024
#define NHEAD 16
#define HDIM 64
#define SEQ 2048
#define BATCH 2
#define M_TOT (BATCH * SEQ) // 4096 tokens
#define NQKV 3072           // fused QKV output cols

typedef __attribute__((ext_vector_type(8))) short bf16x8;  // 8 bf16 = 4 VGPRs (MFMA A/B frag)
typedef __attribute__((ext_vector_type(4))) float f32x4;   // 16x16 MFMA C/D frag
typedef __attribute__((ext_vector_type(16))) float f32x16; // 32x32 MFMA C/D frag

// (1/sqrt(HDIM)) * log2(e), folded into Q at the QKV-GEMM epilogue
#define C2_SCALE 0.18033688f

__device__ __forceinline__ unsigned short f2bf(float f) {
  union { float f; unsigned int u; } a;
  a.f = f;
  unsigned int u = a.u;
  return (unsigned short)((u + 0x7fffu + ((u >> 16) & 1u)) >> 16); // RNE
}

// packed f32x2 -> bf16x2 (v_cvt_pk_bf16_f32), low short = first arg
__device__ __forceinline__ unsigned int pkbf(float a, float b) {
  union { __hip_bfloat162 h; unsigned int u; } cv;
  cv.h = __float22bfloat162_rn(float2{a, b});
  return cv.u;
}

__device__ __forceinline__ float fast_exp2(float x) {
#if defined(__has_builtin) && __has_builtin(__builtin_amdgcn_exp2f)
  return __builtin_amdgcn_exp2f(x);
#else
  return exp2f(x);
#endif
}

// async global->LDS, 16B per lane. LDS dest is wave-uniform base + lane*16.
typedef const __attribute__((address_space(1))) void* gas1_t;
typedef __attribute__((address_space(3))) void* las3_t;
__device__ __forceinline__ void gload16(const void* g, void* l) {
  __builtin_amdgcn_global_load_lds((gas1_t)(unsigned long long)g,
                                   (las3_t)(unsigned int)(unsigned long long)l,
                                   16, 0, 0);
}

// ---------------------------------------------------------------------------
// 4x4 transpose across groups of 4 consecutive lanes (element-wise verified):
// in: lane c (=lane&3) holds column (base+c) of a 4x4 tile, rows in a0..a3.
// out: lane c holds row (base_row+c), columns in a0..a3.
// Stage 1 (xor 2): swap off-diagonal 2x2 blocks. Stage 2 (xor 1): transpose
// within 2x2 blocks.
// ---------------------------------------------------------------------------
__device__ __forceinline__ void quad_transpose4(float& a0, float& a1, float& a2,
                                                float& a3, int lane) {
  const int c = lane & 3;
  float u0 = (c & 2) ? a0 : a2;
  float u1 = (c & 2) ? a1 : a3;
  u0 = __shfl_xor(u0, 2, 64);
  u1 = __shfl_xor(u1, 2, 64);
  a0 = (c & 2) ? u0 : a0;
  a1 = (c & 2) ? u1 : a1;
  a2 = (c & 2) ? a2 : u0;
  a3 = (c & 2) ? a3 : u1;
  float v0 = (c & 1) ? a0 : a1;
  float v1 = (c & 1) ? a2 : a3;
  v0 = __shfl_xor(v0, 1, 64);
  v1 = __shfl_xor(v1, 1, 64);
  a0 = (c & 1) ? v0 : a0;
  a2 = (c & 1) ? v1 : a2;
  a1 = (c & 1) ? a1 : v0;
  a3 = (c & 1) ? a3 : v1;
}

// ---------------------------------------------------------------------------
// Kernel 1 (fused): LayerNorm rows (blocks 0..4095) + weight bf16 cast
// (blocks 4096..8191).
// ---------------------------------------------------------------------------
__global__ __launch_bounds__(256) void ln_cast_kernel(const float* __restrict__ x,
                                                      const float* __restrict__ gamma,
                                                      const float* __restrict__ beta,
                                                      unsigned short* __restrict__ xn,
                                                      const float* __restrict__ w0,
                                                      const float* __restrict__ w1,
                                                      const float* __restrict__ w2,
                                                      const float* __restrict__ w3,
                                                      unsigned short* __restrict__ wdst) {
  const int t = threadIdx.x;
  if (blockIdx.x >= M_TOT) {
    const int cb = blockIdx.x - M_TOT;   // 0..4095
    const int y = cb >> 10;              // matrix index 0..3
    const float* s = (y == 0) ? w0 : (y == 1) ? w1 : (y == 2) ? w2 : w3;
    const int i = (cb & 1023) * 256 + t; // float4 index within matrix
    const float4 v = ((const float4*)s)[i];
    ushort4 o;
    o.x = f2bf(v.x);
    o.y = f2bf(v.y);
    o.z = f2bf(v.z);
    o.w = f2bf(v.w);
    ((ushort4*)(wdst + (size_t)y * H * H))[i] = o;
    return;
  }
  const int row = blockIdx.x;
  const float* xr = x + (size_t)row * H;
  float4 v = ((const float4*)xr)[t];
  float s = v.x + v.y + v.z + v.w;
  float s2 = v.x * v.x + v.y * v.y + v.z * v.z + v.w * v.w;
#pragma unroll
  for (int o = 32; o; o >>= 1) {
    s += __shfl_xor(s, o, 64);
    s2 += __shfl_xor(s2, o, 64);
  }
  __shared__ float red[8];
  const int wave = t >> 6;
  if ((t & 63) == 0) {
    red[wave] = s;
    red[wave + 4] = s2;
  }
  __syncthreads();
  const float ts = red[0] + red[1] + red[2] + red[3];
  const float ts2 = red[4] + red[5] + red[6] + red[7];
  const float mu = ts * (1.0f / (float)H);
  const float var = ts2 * (1.0f / (float)H) - mu * mu;
  const float rstd = rsqrtf(var + 1e-5f);
  const float4 g = ((const float4*)gamma)[t];
  const float4 b = ((const float4*)beta)[t];
  ushort4 o;
  o.x = f2bf((v.x - mu) * rstd * g.x + b.x);
  o.y = f2bf((v.y - mu) * rstd * g.y + b.y);
  o.z = f2bf((v.z - mu) * rstd * g.z + b.z);
  o.w = f2bf((v.w - mu) * rstd * g.w + b.w);
  ((ushort4*)(xn + (size_t)row * H))[t] = o;
}

// ---------------------------------------------------------------------------
// QKV GEMM v12: 128x128x(BK=32), 3-buffer counted-vmcnt pipeline (as v11)
// + VECTORIZED Q/K EPILOGUE: quad_transpose4 puts 4 consecutive cols of one
// row in each lane -> one ushort4 store per (i,j) instead of 4 scalar 2B
// stores (64 -> 16 store instrs per lane).
// ---------------------------------------------------------------------------
template <int EPI, int NPX>
__global__ __launch_bounds__(256, 3) void gemm128p(const unsigned short* __restrict__ A,
                                                   const unsigned short* __restrict__ W,
                                                   unsigned short* __restrict__ qk,
                                                   unsigned short* __restrict__ vt,
                                                   const float* __restrict__ bo,
                                                   const float* __restrict__ x,
                                                   float* __restrict__ out) {
  const int id = blockIdx.x;
  const int xcd = id & 7;
  const int r = id >> 3;
  const int nb = xcd * NPX + (r % NPX);
  const int mb = r / NPX;
  const int m0 = mb * 128;
  const int n0 = nb * 128;
  const int tid = threadIdx.x;
  const int wave = tid >> 6;
  const int lane = tid & 63;
  const int l16 = lane & 15;
  const int quad = lane >> 4;
  const int wx = wave & 1, wy = wave >> 1;

  __shared__ __align__(16) unsigned short As[3][128 * 32];
  __shared__ __align__(16) unsigned short Bs[3][128 * 32];

  // staging: wave stages 32 rows (2 gload16 instrs per matrix) = 4 instrs
  const int sub = lane >> 2;       // row within 16-row group
  const int kcol = (lane & 3) * 8; // 4 lanes cover 32 cols
  const unsigned short* ag = A + (size_t)(m0 + wave * 32 + sub) * H + kcol;
  const unsigned short* bg = W + (size_t)(n0 + wave * 32 + sub) * H + kcol;
  const int lofs = wave * 32 * 32;

  f32x4 acc[4][4] = {};

  auto stage = [&](int t, int B) {
    const int k1 = t * 32;
    gload16(ag + k1, &As[B][lofs]);
    gload16(ag + k1 + 16 * H, &As[B][lofs + 16 * 32]);
    gload16(bg + k1, &Bs[B][lofs]);
    gload16(bg + k1 + 16 * H, &Bs[B][lofs + 16 * 32]);
  };
  auto compute = [&](int bi) {
    bf16x8 af[4], bf[4];
#pragma unroll
    for (int t = 0; t < 4; t++) {
      af[t] = *(const bf16x8*)&As[bi][(wy * 64 + t * 16 + l16) * 32 + quad * 8];
      bf[t] = *(const bf16x8*)&Bs[bi][(wx * 64 + t * 16 + l16) * 32 + quad * 8];
    }
#pragma unroll
    for (int i = 0; i < 4; i++)
#pragma unroll
      for (int j = 0; j < 4; j++)
        acc[i][j] = __builtin_amdgcn_mfma_f32_16x16x32_bf16(af[i], bf[j], acc[i][j], 0, 0, 0);
  };

  // prologue: stage tiles 0,1 (8 loads/wave outstanding)
  stage(0, 0);
  stage(1, 1);

  for (int it = 0; it < H / 32 - 1; it++) {
    asm volatile("s_waitcnt vmcnt(4)" ::: "memory"); // tile it landed (own)
    __builtin_amdgcn_s_barrier();                    // all waves' tile it landed
    if (it + 2 < H / 32) stage(it + 2, (it + 2) % 3);
    compute(it % 3);
  }
  // peeled last iteration: drain everything
  asm volatile("s_waitcnt vmcnt(0)" ::: "memory");
  __builtin_amdgcn_s_barrier();
  compute((H / 32 - 1) % 3);

  if (EPI == 0) {
#pragma unroll
    for (int j = 0; j < 4; j++) {
      const int cb = n0 + wx * 64 + j * 16; // wave-uniform tile col base
      if (cb < 2048) {
        const float qs = (cb < 1024) ? C2_SCALE : 1.0f;
#pragma unroll
        for (int i = 0; i < 4; i++) {
          float a0 = acc[i][j][0] * qs, a1 = acc[i][j][1] * qs;
          float a2 = acc[i][j][2] * qs, a3 = acc[i][j][3] * qs;
          quad_transpose4(a0, a1, a2, a3, lane);
          // lane now holds row (row0 + (lane&3)), cols cb+(l16&12)+0..3
          const int row = m0 + wy * 64 + i * 16 + quad * 4 + (lane & 3);
          const int col = cb + (l16 & 12);
          uint2 d;
          d.x = pkbf(a0, a1);
          d.y = pkbf(a2, a3);
          *(uint2*)&qk[(size_t)row * 2048 + col] = d;
        }
      } else {
        const int n = cb + l16 - 2048; // h*64+d
#pragma unroll
        for (int i = 0; i < 4; i++) {
          const int row0 = m0 + wy * 64 + i * 16 + quad * 4;
          const int b = row0 >> 11;
          const int s = row0 & 2047;
          ushort4 p;
          p.x = f2bf(acc[i][j][0]);
          p.y = f2bf(acc[i][j][1]);
          p.z = f2bf(acc[i][j][2]);
          p.w = f2bf(acc[i][j][3]);
          *(ushort4*)&vt[((size_t)b * 1024 + n) * SEQ + s] = p;
        }
      }
    }
  } else {
#pragma unroll
    for (int j = 0; j < 4; j++) {
      const int col = n0 + wx * 64 + j * 16 + l16;
      const float bv = bo[col];
#pragma unroll
      for (int i = 0; i < 4; i++) {
        const int row = m0 + wy * 64 + i * 16 + quad * 4;
#pragma unroll
        for (int r2 = 0; r2 < 4; r2++) {
          const size_t idx = (size_t)(row + r2) * H + col;
          out[idx] = acc[i][j][r2] + bv + x[idx];
        }
      }
    }
  }
}

// ---------------------------------------------------------------------------
// Proj GEMM v12: 64x128x(BK=32), 3-buffer counted-vmcnt pipeline (as v11)
// + VECTORIZED EPILOGUE: quad_transpose4 -> float4 residual loads + float4
// stores (full 64B cachelines), 8 loads + 8 stores per lane instead of 32+32.
// ---------------------------------------------------------------------------
__global__ __launch_bounds__(256, 4) void proj64p(const unsigned short* __restrict__ A,
                                                  const unsigned short* __restrict__ W,
                                                  const float* __restrict__ bo,
                                                  const float* __restrict__ x,
                                                  float* __restrict__ out) {
  const int id = blockIdx.x; // 512 blocks
  const int nb = id & 7;     // N-block = XCD
  const int mb = id >> 3;    // 0..63
  const int m0 = mb * 64;
  const int n0 = nb * 128;
  const int tid = threadIdx.x;
  const int wave = tid >> 6;
  const int lane = tid & 63;
  const int l16 = lane & 15;
  const int quad = lane >> 4;
  const int wx = wave & 1, wy = wave >> 1;

  __shared__ __align__(16) unsigned short As[3][64 * 32];
  __shared__ __align__(16) unsigned short Bs[3][128 * 32];

  // staging: wave stages 16 A-rows (1 gload16) + 32 B-rows (2 gload16)
  const int sub = lane >> 2;       // row within 16-row group
  const int kcol = (lane & 3) * 8; // 4 lanes cover 32 cols
  const unsigned short* ag = A + (size_t)(m0 + wave * 16 + sub) * H + kcol;
  const unsigned short* bg = W + (size_t)(n0 + wave * 32 + sub) * H + kcol;
  const int lofsA = wave * 16 * 32;
  const int lofsB = wave * 32 * 32;

  f32x4 acc[2][4] = {};

  auto stage = [&](int t, int B) {
    const int k1 = t * 32;
    gload16(ag + k1, &As[B][lofsA]);
    gload16(bg + k1, &Bs[B][lofsB]);
    gload16(bg + k1 + 16 * H, &Bs[B][lofsB + 16 * 32]);
  };
  auto compute = [&](int bi) {
    bf16x8 af[2], bf[4];
#pragma unroll
    for (int t = 0; t < 2; t++)
      af[t] = *(const bf16x8*)&As[bi][(wy * 32 + t * 16 + l16) * 32 + quad * 8];
#pragma unroll
    for (int t = 0; t < 4; t++)
      bf[t] = *(const bf16x8*)&Bs[bi][(wx * 64 + t * 16 + l16) * 32 + quad * 8];
#pragma unroll
    for (int i = 0; i < 2; i++)
#pragma unroll
      for (int j = 0; j < 4; j++)
        acc[i][j] = __builtin_amdgcn_mfma_f32_16x16x32_bf16(af[i], bf[j], acc[i][j], 0, 0, 0);
  };

  stage(0, 0);
  stage(1, 1); // 6 loads/wave outstanding

  for (int it = 0; it < H / 32 - 1; it++) {
    asm volatile("s_waitcnt vmcnt(3)" ::: "memory"); // tile it landed (own)
    __builtin_amdgcn_s_barrier();
    if (it + 2 < H / 32) stage(it + 2, (it + 2) % 3);
    compute(it % 3);
  }
  asm volatile("s_waitcnt vmcnt(0)" ::: "memory");
  __builtin_amdgcn_s_barrier();
  compute((H / 32 - 1) % 3);

#pragma unroll
  for (int j = 0; j < 4; j++) {
    const int colb = n0 + wx * 64 + j * 16 + (l16 & 12); // lane's 4-col base
    const float4 bv4 = *(const float4*)&bo[colb];
#pragma unroll
    for (int i = 0; i < 2; i++) {
      float a0 = acc[i][j][0], a1 = acc[i][j][1];
      float a2 = acc[i][j][2], a3 = acc[i][j][3];
      quad_transpose4(a0, a1, a2, a3, lane);
      const int row = m0 + wy * 32 + i * 16 + quad * 4 + (lane & 3);
      const size_t idx = (size_t)row * H + colb;
      const float4 xr = *(const float4*)&x[idx];
      float4 o;
      o.x = a0 + bv4.x + xr.x;
      o.y = a1 + bv4.y + xr.y;
      o.z = a2 + bv4.z + xr.z;
      o.w = a3 + bv4.w + xr.w;
      *(float4*)&out[idx] = o;
    }
  }
}

// ---------------------------------------------------------------------------
// Flash attention v10 (best: 46.9 us — UNCHANGED, control):
// 32x32x16 in-register-P, KVBLK=128, 16 iters, LDS 64 KB, 512 blocks.
// ---------------------------------------------------------------------------
__global__ __launch_bounds__(256, 2) void attn_kernel(const unsigned short* __restrict__ qk,
                                                      const unsigned short* __restrict__ vt,
                                                      unsigned short* __restrict__ O) {
  const int id = blockIdx.x; // 512 blocks
  const int xcd = id & 7;
  const int slot = id >> 3;       // 0..63
  const int qt = slot & 15;       // q-tile within (b,h)
  const int g = slot >> 4;        // 0..3
  const int combo = xcd * 4 + g;  // 0..31
  const int h = combo & 15;
  const int b = combo >> 4;
  const int tid = threadIdx.x;
  const int wave = tid >> 6;
  const int lane = tid & 63;
  const int l31 = lane & 31;
  const int l7 = lane & 7;
  const int hi = lane >> 5;

  __shared__ __align__(16) unsigned short Kt[2][128 * 64];   // [s][d] 32 KB
  __shared__ __align__(16) unsigned short Vt[2][2][64 * 64]; // [half][d][s] 32 KB

  const unsigned short* Qbase = qk + (size_t)b * SEQ * 2048 + h * 64;
  const unsigned short* Kbase = qk + (size_t)b * SEQ * 2048 + 1024 + h * 64;
  const unsigned short* Vbase = vt + ((size_t)b * 1024 + h * 64) * SEQ;

  // staging geometry: one gload16 covers 8 rows x 64 shorts (1 KB), XOR swizzle
  const int rIn = lane >> 3;
  const int gsw = (lane & 7) ^ rIn;

  // Q fragments (B-operand, hoisted): B[n=l31 -> qrow][k=hi*8+e -> d in chunk kc]
  const int qrow = qt * 128 + wave * 32 + l31;
  bf16x8 aq[4];
#pragma unroll
  for (int kc = 0; kc < 4; kc++)
    aq[kc] = *(const bf16x8*)(Qbase + (size_t)qrow * 2048 + kc * 16 + hi * 8);

  f32x16 o_acc[2] = {}; // [dt] O^T: col=l31=qrow, row=(reg&3)+8*(reg>>2)+4*hi -> d
  float lc[4] = {};     // partial denominators (4 chains)

  // prologue: stage tile 0 into buffer 0 (4 K-chunks + 4 V-chunks per wave)
#pragma unroll
  for (int c = 0; c < 4; c++) {
    const int ch = wave * 4 + c; // 0..15
    const int krow = ch * 8 + rIn;
    gload16(Kbase + (size_t)krow * 2048 + gsw * 8, &Kt[0][ch * 512]);
    const int half = ch >> 3, sub = ch & 7;
    const int vrow = sub * 8 + rIn;
    gload16(Vbase + (size_t)vrow * SEQ + half * 64 + gsw * 8, &Vt[0][half][sub * 512]);
  }

#pragma unroll 2
  for (int it = 0; it < SEQ / 128; it++) {
    const int bi = it & 1;
    __syncthreads(); // waits cur-buffer loads (vmcnt) + prev iter readers done
    if (it + 1 < SEQ / 128) {
#pragma unroll
      for (int c = 0; c < 4; c++) {
        const int ch = wave * 4 + c;
        const int krow = ch * 8 + rIn;
        gload16(Kbase + (size_t)((it + 1) * 128 + krow) * 2048 + gsw * 8,
                &Kt[bi ^ 1][ch * 512]);
        const int half = ch >> 3, sub = ch & 7;
        const int vrow = sub * 8 + rIn;
        gload16(Vbase + (size_t)vrow * SEQ + (it + 1) * 128 + half * 64 + gsw * 8,
                &Vt[bi ^ 1][half][sub * 512]);
      }
    }

    unsigned int w[4][8]; // [mt][gi]: P words for s = 32*mt + pattern

    // ---- pass A: mt 0,1 -> QK, softmax ----
    {
      f32x16 sa = {}, sb = {};
#pragma unroll
      for (int kc = 0; kc < 4; kc++) {
        const bf16x8 kf0 = *(const bf16x8*)&Kt[bi][(l31)*64 + ((kc * 16 + hi * 8) ^ (l7 * 8))];
        const bf16x8 kf1 =
            *(const bf16x8*)&Kt[bi][(32 + l31) * 64 + ((kc * 16 + hi * 8) ^ (l7 * 8))];
        sa = __builtin_amdgcn_mfma_f32_32x32x16_bf16(kf0, aq[kc], sa, 0, 0, 0);
        sb = __builtin_amdgcn_mfma_f32_32x32x16_bf16(kf1, aq[kc], sb, 0, 0, 0);
      }
      {
        float p[16];
#pragma unroll
        for (int r2 = 0; r2 < 16; r2++) p[r2] = fast_exp2(sa[r2]);
        lc[0] += ((p[0] + p[1]) + (p[2] + p[3])) + ((p[8] + p[9]) + (p[10] + p[11]));
        lc[1] += ((p[4] + p[5]) + (p[6] + p[7])) + ((p[12] + p[13]) + (p[14] + p[15]));
#pragma unroll
        for (int gi = 0; gi < 8; gi++) w[0][gi] = pkbf(p[2 * gi], p[2 * gi + 1]);
      }
      {
        float p[16];
#pragma unroll
        for (int r2 = 0; r2 < 16; r2++) p[r2] = fast_exp2(sb[r2]);
        lc[2] += ((p[0] + p[1]) + (p[2] + p[3])) + ((p[8] + p[9]) + (p[10] + p[11]));
        lc[3] += ((p[4] + p[5]) + (p[6] + p[7])) + ((p[12] + p[13]) + (p[14] + p[15]));
#pragma unroll
        for (int gi = 0; gi < 8; gi++) w[1][gi] = pkbf(p[2 * gi], p[2 * gi + 1]);
      }
    }

    // ---- pass B: mt 2,3 -> QK, softmax ----
    {
      f32x16 sa = {}, sb = {};
#pragma unroll
      for (int kc = 0; kc < 4; kc++) {
        const bf16x8 kf0 =
            *(const bf16x8*)&Kt[bi][(64 + l31) * 64 + ((kc * 16 + hi * 8) ^ (l7 * 8))];
        const bf16x8 kf1 =
            *(const bf16x8*)&Kt[bi][(96 + l31) * 64 + ((kc * 16 + hi * 8) ^ (l7 * 8))];
        sa = __builtin_amdgcn_mfma_f32_32x32x16_bf16(kf0, aq[kc], sa, 0, 0, 0);
        sb = __builtin_amdgcn_mfma_f32_32x32x16_bf16(kf1, aq[kc], sb, 0, 0, 0);
      }
      {
        float p[16];
#pragma unroll
        for (int r2 = 0; r2 < 16; r2++) p[r2] = fast_exp2(sa[r2]);
        lc[0] += ((p[0] + p[1]) + (p[2] + p[3])) + ((p[8] + p[9]) + (p[10] + p[11]));
        lc[1] += ((p[4] + p[5]) + (p[6] + p[7])) + ((p[12] + p[13]) + (p[14] + p[15]));
#pragma unroll
        for (int gi = 0; gi < 8; gi++) w[2][gi] = pkbf(p[2 * gi], p[2 * gi + 1]);
      }
      {
        float p[16];
#pragma unroll
        for (int r2 = 0; r2 < 16; r2++) p[r2] = fast_exp2(sb[r2]);
        lc[2] += ((p[0] + p[1]) + (p[2] + p[3])) + ((p[8] + p[9]) + (p[10] + p[11]));
        lc[3] += ((p[4] + p[5]) + (p[6] + p[7])) + ((p[12] + p[13]) + (p[14] + p[15]));
#pragma unroll
        for (int gi = 0; gi < 8; gi++) w[3][gi] = pkbf(p[2 * gi], p[2 * gi + 1]);
      }
    }

    // ---- PV: O^T += V^T (A) @ P^T (B), 8 s-chunks ----
#pragma unroll
    for (int sc = 0; sc < 8; sc++) {
      const int n0i = 2 * sc, n1i = 2 * sc + 1;
      const int mt0 = n0i >> 2, b0 = n0i & 3;
      const int mt1 = n1i >> 2, b1 = n1i & 3;
      const auto rA = __builtin_amdgcn_permlane32_swap(w[mt0][2 * b0], w[mt1][2 * b1],
                                                       false, false);
      const auto rB = __builtin_amdgcn_permlane32_swap(w[mt0][2 * b0 + 1], w[mt1][2 * b1 + 1],
                                                       false, false);
      union { unsigned int u[4]; bf16x8 v; } pb;
      pb.u[0] = rA[0]; // k = sc*16+hi*8 + {0,1}
      pb.u[1] = rB[0]; // + {2,3}
      pb.u[2] = rA[1]; // + {4,5}
      pb.u[3] = rB[1]; // + {6,7}
      const int half = sc >> 2, sch = sc & 3;
#pragma unroll
      for (int dt = 0; dt < 2; dt++) {
        const bf16x8 vf = *(const bf16x8*)&Vt[bi][half][(dt * 32 + l31) * 64 +
                                                       ((sch * 16 + hi * 8) ^ (l7 * 8))];
        o_acc[dt] = __builtin_amdgcn_mfma_f32_32x32x16_bf16(vf, pb.v, o_acc[dt], 0, 0, 0);
      }
    }
  }

  // epilogue: lanes l and l|32 hold complementary s-subsets of the same qrow
  float lsum = (lc[0] + lc[1]) + (lc[2] + lc[3]);
  const float l_i = lsum + __shfl_xor(lsum, 32, 64);
  const float inv = 1.0f / l_i;
  unsigned short* orow = O + ((size_t)(b * SEQ + qrow)) * H + h * 64;
#pragma unroll
  for (int dt = 0; dt < 2; dt++)
#pragma unroll
    for (int rg = 0; rg < 4; rg++) {
      uint2 d;
      d.x = pkbf(o_acc[dt][4 * rg + 0] * inv, o_acc[dt][4 * rg + 1] * inv);
      d.y = pkbf(o_acc[dt][4 * rg + 2] * inv, o_acc[dt][4 * rg + 3] * inv);
      *(uint2*)&orow[dt * 32 + 8 * rg + 4 * hi] = d;
    }
}

// ---------------------------------------------------------------------------
extern "C" void kernel_launch(void* const* d_in, const int* in_sizes, int n_in,
                              void* d_out, int out_size, void* d_ws, size_t ws_size,
                              hipStream_t stream) {
  const float* x = (const float*)d_in[0];
  const float* Wq = (const float*)d_in[1];
  const float* Wk = (const float*)d_in[2];
  const float* Wv = (const float*)d_in[3];
  const float* Wo = (const float*)d_in[4];
  const float* bo = (const float*)d_in[5];
  const float* gamma = (const float*)d_in[6];
  const float* beta = (const float*)d_in[7];
  float* out = (float*)d_out;

  unsigned short* ws = (unsigned short*)d_ws;
  unsigned short* xn = ws;                              // 4096*1024
  unsigned short* wcat = xn + (size_t)M_TOT * H;        // 4*1024*1024 (Wq,Wk,Wv,Wo)
  unsigned short* wob = wcat + (size_t)3 * H * H;
  unsigned short* qkb = wcat + (size_t)4 * H * H;       // 4096*2048 (Q | K)
  unsigned short* vtb = qkb + (size_t)M_TOT * 2048;     // 2*1024*2048 (V^T)
  unsigned short* atb = vtb + (size_t)BATCH * H * SEQ;  // 4096*1024

  ln_cast_kernel<<<M_TOT + 4096, 256, 0, stream>>>(x, gamma, beta, xn, Wq, Wk, Wv, Wo,
                                                   wcat);
  // QKV: 32 M-blocks x 24 N-blocks, XCD-supertiled (3 N-blocks per XCD)
  gemm128p<0, 3><<<(M_TOT / 128) * (NQKV / 128), 256, 0, stream>>>(
      xn, wcat, qkb, vtb, nullptr, nullptr, nullptr);
  // attn: 512 blocks (128-row q-tiles), XCD-supertiled (4 (b,h) combos per XCD)
  attn_kernel<<<(SEQ / 128) * NHEAD * BATCH, 256, 0, stream>>>(qkb, vtb, atb);
  // proj: 64 M-blocks x 8 N-blocks = 512 blocks (2 blocks/CU)
  proj64p<<<(M_TOT / 64) * (H / 128), 256, 0, stream>>>(atb, wob, bo, x, out);
}

// Round 9
// 186.660 us; speedup vs baseline: 1.0016x; 1.0016x over previous
//
#include <hip/hip_runtime.h>
#include <hip/hip_bf16.h>

// Problem constants
#define H 1024
#define NHEAD 16
#define HDIM 64
#define SEQ 2048
#define BATCH 2
#define M_TOT (BATCH * SEQ) // 4096 tokens
#define NQKV 3072           // fused QKV output cols

typedef __attribute__((ext_vector_type(8))) short bf16x8;  // 8 bf16 = 4 VGPRs (MFMA A/B frag)
typedef __attribute__((ext_vector_type(4))) float f32x4;   // 16x16 MFMA C/D frag
typedef __attribute__((ext_vector_type(16))) float f32x16; // 32x32 MFMA C/D frag

// (1/sqrt(HDIM)) * log2(e), folded into Q at the QKV-GEMM epilogue
#define C2_SCALE 0.18033688f

__device__ __forceinline__ unsigned short f2bf(float f) {
  union { float f; unsigned int u; } a;
  a.f = f;
  unsigned int u = a.u;
  return (unsigned short)((u + 0x7fffu + ((u >> 16) & 1u)) >> 16); // RNE
}

// packed f32x2 -> bf16x2 (v_cvt_pk_bf16_f32), low short = first arg
__device__ __forceinline__ unsigned int pkbf(float a, float b) {
  union { __hip_bfloat162 h; unsigned int u; } cv;
  cv.h = __float22bfloat162_rn(float2{a, b});
  return cv.u;
}

__device__ __forceinline__ float fast_exp2(float x) {
#if defined(__has_builtin) && __has_builtin(__builtin_amdgcn_exp2f)
  return __builtin_amdgcn_exp2f(x);
#else
  return exp2f(x);
#endif
}

// async global->LDS, 16B per lane. LDS dest is wave-uniform base + lane*16.
typedef const __attribute__((address_space(1))) void* gas1_t;
typedef __attribute__((address_space(3))) void* las3_t;
__device__ __forceinline__ void gload16(const void* g, void* l) {
  __builtin_amdgcn_global_load_lds((gas1_t)(unsigned long long)g,
                                   (las3_t)(unsigned int)(unsigned long long)l,
                                   16, 0, 0);
}

// ---------------------------------------------------------------------------
// Kernel 1 (fused): LayerNorm rows (blocks 0..4095) + weight bf16 cast
// (blocks 4096..8191).
// ---------------------------------------------------------------------------
__global__ __launch_bounds__(256) void ln_cast_kernel(const float* __restrict__ x,
                                                      const float* __restrict__ gamma,
                                                      const float* __restrict__ beta,
                                                      unsigned short* __restrict__ xn,
                                                      const float* __restrict__ w0,
                                                      const float* __restrict__ w1,
                                                      const float* __restrict__ w2,
                                                      const float* __restrict__ w3,
                                                      unsigned short* __restrict__ wdst) {
  const int t = threadIdx.x;
  if (blockIdx.x >= M_TOT) {
    const int cb = blockIdx.x - M_TOT;   // 0..4095
    const int y = cb >> 10;              // matrix index 0..3
    const float* s = (y == 0) ? w0 : (y == 1) ? w1 : (y == 2) ? w2 : w3;
    const int i = (cb & 1023) * 256 + t; // float4 index within matrix
    const float4 v = ((const float4*)s)[i];
    ushort4 o;
    o.x = f2bf(v.x);
    o.y = f2bf(v.y);
    o.z = f2bf(v.z);
    o.w = f2bf(v.w);
    ((ushort4*)(wdst + (size_t)y * H * H))[i] = o;
    return;
  }
  const int row = blockIdx.x;
  const float* xr = x + (size_t)row * H;
  float4 v = ((const float4*)xr)[t];
  float s = v.x + v.y + v.z + v.w;
  float s2 = v.x * v.x + v.y * v.y + v.z * v.z + v.w * v.w;
#pragma unroll
  for (int o = 32; o; o >>= 1) {
    s += __shfl_xor(s, o, 64);
    s2 += __shfl_xor(s2, o, 64);
  }
  __shared__ float red[8];
  const int wave = t >> 6;
  if ((t & 63) == 0) {
    red[wave] = s;
    red[wave + 4] = s2;
  }
  __syncthreads();
  const float ts = red[0] + red[1] + red[2] + red[3];
  const float ts2 = red[4] + red[5] + red[6] + red[7];
  const float mu = ts * (1.0f / (float)H);
  const float var = ts2 * (1.0f / (float)H) - mu * mu;
  const float rstd = rsqrtf(var + 1e-5f);
  const float4 g = ((const float4*)gamma)[t];
  const float4 b = ((const float4*)beta)[t];
  ushort4 o;
  o.x = f2bf((v.x - mu) * rstd * g.x + b.x);
  o.y = f2bf((v.y - mu) * rstd * g.y + b.y);
  o.z = f2bf((v.z - mu) * rstd * g.z + b.z);
  o.w = f2bf((v.w - mu) * rstd * g.w + b.w);
  ((ushort4*)(xn + (size_t)row * H))[t] = o;
}

// ---------------------------------------------------------------------------
// QKV GEMM v11 (best measured): 128x128x(BK=32), THREE LDS buffers with a
// 2-tiles-ahead counted-vmcnt pipeline (T4): per iter s_waitcnt vmcnt(4) ->
// raw s_barrier (no drain) -> stage tile it+2 -> ds_read + MFMA.
// LDS 48 KB -> 3 blocks/CU. XCD-supertiled grid (NPX=3). Scalar epilogue
// (v12's vectorized epilogue measured neutral-to-negative; reverted).
// ---------------------------------------------------------------------------
template <int EPI, int NPX>
__global__ __launch_bounds__(256, 3) void gemm128p(const unsigned short* __restrict__ A,
                                                   const unsigned short* __restrict__ W,
                                                   unsigned short* __restrict__ qk,
                                                   unsigned short* __restrict__ vt,
                                                   const float* __restrict__ bo,
                                                   const float* __restrict__ x,
                                                   float* __restrict__ out) {
  const int id = blockIdx.x;
  const int xcd = id & 7;
  const int r = id >> 3;
  const int nb = xcd * NPX + (r % NPX);
  const int mb = r / NPX;
  const int m0 = mb * 128;
  const int n0 = nb * 128;
  const int tid = threadIdx.x;
  const int wave = tid >> 6;
  const int lane = tid & 63;
  const int l16 = lane & 15;
  const int quad = lane >> 4;
  const int wx = wave & 1, wy = wave >> 1;

  __shared__ __align__(16) unsigned short As[3][128 * 32];
  __shared__ __align__(16) unsigned short Bs[3][128 * 32];

  // staging: wave stages 32 rows (2 gload16 instrs per matrix) = 4 instrs
  const int sub = lane >> 2;       // row within 16-row group
  const int kcol = (lane & 3) * 8; // 4 lanes cover 32 cols
  const unsigned short* ag = A + (size_t)(m0 + wave * 32 + sub) * H + kcol;
  const unsigned short* bg = W + (size_t)(n0 + wave * 32 + sub) * H + kcol;
  const int lofs = wave * 32 * 32;

  f32x4 acc[4][4] = {};

  auto stage = [&](int t, int B) {
    const int k1 = t * 32;
    gload16(ag + k1, &As[B][lofs]);
    gload16(ag + k1 + 16 * H, &As[B][lofs + 16 * 32]);
    gload16(bg + k1, &Bs[B][lofs]);
    gload16(bg + k1 + 16 * H, &Bs[B][lofs + 16 * 32]);
  };
  auto compute = [&](int bi) {
    bf16x8 af[4], bf[4];
#pragma unroll
    for (int t = 0; t < 4; t++) {
      af[t] = *(const bf16x8*)&As[bi][(wy * 64 + t * 16 + l16) * 32 + quad * 8];
      bf[t] = *(const bf16x8*)&Bs[bi][(wx * 64 + t * 16 + l16) * 32 + quad * 8];
    }
#pragma unroll
    for (int i = 0; i < 4; i++)
#pragma unroll
      for (int j = 0; j < 4; j++)
        acc[i][j] = __builtin_amdgcn_mfma_f32_16x16x32_bf16(af[i], bf[j], acc[i][j], 0, 0, 0);
  };

  // prologue: stage tiles 0,1 (8 loads/wave outstanding)
  stage(0, 0);
  stage(1, 1);

  for (int it = 0; it < H / 32 - 1; it++) {
    asm volatile("s_waitcnt vmcnt(4)" ::: "memory"); // tile it landed (own)
    __builtin_amdgcn_s_barrier();                    // all waves' tile it landed
    if (it + 2 < H / 32) stage(it + 2, (it + 2) % 3);
    compute(it % 3);
  }
  // peeled last iteration: drain everything
  asm volatile("s_waitcnt vmcnt(0)" ::: "memory");
  __builtin_amdgcn_s_barrier();
  compute((H / 32 - 1) % 3);

  if (EPI == 0) {
#pragma unroll
    for (int j = 0; j < 4; j++) {
      const int cb = n0 + wx * 64 + j * 16; // wave-uniform tile col base
      if (cb < 2048) {
        const float qs = (cb < 1024) ? C2_SCALE : 1.0f;
#pragma unroll
        for (int i = 0; i < 4; i++) {
          const int row = m0 + wy * 64 + i * 16 + quad * 4;
#pragma unroll
          for (int r2 = 0; r2 < 4; r2++)
            qk[(size_t)(row + r2) * 2048 + cb + l16] = f2bf(acc[i][j][r2] * qs);
        }
      } else {
        const int n = cb + l16 - 2048; // h*64+d
#pragma unroll
        for (int i = 0; i < 4; i++) {
          const int row0 = m0 + wy * 64 + i * 16 + quad * 4;
          const int b = row0 >> 11;
          const int s = row0 & 2047;
          ushort4 p;
          p.x = f2bf(acc[i][j][0]);
          p.y = f2bf(acc[i][j][1]);
          p.z = f2bf(acc[i][j][2]);
          p.w = f2bf(acc[i][j][3]);
          *(ushort4*)&vt[((size_t)b * 1024 + n) * SEQ + s] = p;
        }
      }
    }
  } else {
#pragma unroll
    for (int j = 0; j < 4; j++) {
      const int col = n0 + wx * 64 + j * 16 + l16;
      const float bv = bo[col];
#pragma unroll
      for (int i = 0; i < 4; i++) {
        const int row = m0 + wy * 64 + i * 16 + quad * 4;
#pragma unroll
        for (int r2 = 0; r2 < 4; r2++) {
          const size_t idx = (size_t)(row + r2) * H + col;
          out[idx] = acc[i][j][r2] + bv + x[idx];
        }
      }
    }
  }
}

// ---------------------------------------------------------------------------
// Proj GEMM v11 (best measured): 64x128x(BK=32), 3-buffer counted-vmcnt
// pipeline (3 loads/stage -> vmcnt(3)). LDS 36 KB. Grid 512 = 2 blocks/CU.
// Scalar epilogue (v12 vectorization reverted). id&7 = N-block (== XCD).
// ---------------------------------------------------------------------------
__global__ __launch_bounds__(256, 4) void proj64p(const unsigned short* __restrict__ A,
                                                  const unsigned short* __restrict__ W,
                                                  const float* __restrict__ bo,
                                                  const float* __restrict__ x,
                                                  float* __restrict__ out) {
  const int id = blockIdx.x; // 512 blocks
  const int nb = id & 7;     // N-block = XCD
  const int mb = id >> 3;    // 0..63
  const int m0 = mb * 64;
  const int n0 = nb * 128;
  const int tid = threadIdx.x;
  const int wave = tid >> 6;
  const int lane = tid & 63;
  const int l16 = lane & 15;
  const int quad = lane >> 4;
  const int wx = wave & 1, wy = wave >> 1;

  __shared__ __align__(16) unsigned short As[3][64 * 32];
  __shared__ __align__(16) unsigned short Bs[3][128 * 32];

  // staging: wave stages 16 A-rows (1 gload16) + 32 B-rows (2 gload16)
  const int sub = lane >> 2;       // row within 16-row group
  const int kcol = (lane & 3) * 8; // 4 lanes cover 32 cols
  const unsigned short* ag = A + (size_t)(m0 + wave * 16 + sub) * H + kcol;
  const unsigned short* bg = W + (size_t)(n0 + wave * 32 + sub) * H + kcol;
  const int lofsA = wave * 16 * 32;
  const int lofsB = wave * 32 * 32;

  f32x4 acc[2][4] = {};

  auto stage = [&](int t, int B) {
    const int k1 = t * 32;
    gload16(ag + k1, &As[B][lofsA]);
    gload16(bg + k1, &Bs[B][lofsB]);
    gload16(bg + k1 + 16 * H, &Bs[B][lofsB + 16 * 32]);
  };
  auto compute = [&](int bi) {
    bf16x8 af[2], bf[4];
#pragma unroll
    for (int t = 0; t < 2; t++)
      af[t] = *(const bf16x8*)&As[bi][(wy * 32 + t * 16 + l16) * 32 + quad * 8];
#pragma unroll
    for (int t = 0; t < 4; t++)
      bf[t] = *(const bf16x8*)&Bs[bi][(wx * 64 + t * 16 + l16) * 32 + quad * 8];
#pragma unroll
    for (int i = 0; i < 2; i++)
#pragma unroll
      for (int j = 0; j < 4; j++)
        acc[i][j] = __builtin_amdgcn_mfma_f32_16x16x32_bf16(af[i], bf[j], acc[i][j], 0, 0, 0);
  };

  stage(0, 0);
  stage(1, 1); // 6 loads/wave outstanding

  for (int it = 0; it < H / 32 - 1; it++) {
    asm volatile("s_waitcnt vmcnt(3)" ::: "memory"); // tile it landed (own)
    __builtin_amdgcn_s_barrier();
    if (it + 2 < H / 32) stage(it + 2, (it + 2) % 3);
    compute(it % 3);
  }
  asm volatile("s_waitcnt vmcnt(0)" ::: "memory");
  __builtin_amdgcn_s_barrier();
  compute((H / 32 - 1) % 3);

#pragma unroll
  for (int j = 0; j < 4; j++) {
    const int col = n0 + wx * 64 + j * 16 + l16;
    const float bv = bo[col];
#pragma unroll
    for (int i = 0; i < 2; i++) {
      const int row = m0 + wy * 32 + i * 16 + quad * 4;
#pragma unroll
      for (int r2 = 0; r2 < 4; r2++) {
        const size_t idx = (size_t)(row + r2) * H + col;
        out[idx] = acc[i][j][r2] + bv + x[idx];
      }
    }
  }
}

// ---------------------------------------------------------------------------
// Flash attention v13: v10 structure (32x32x16 in-register-P, KVBLK=128,
// 16 iters, LDS 64 KB, 512 blocks) + T5 s_setprio(1) around the pure-MFMA
// clusters (QK kc-loops, PV MFMA pairs). m191: setprio +4-7% on attn with
// independent blocks at uncorrelated phases — exactly this regime (2
// independent blocks/CU, no inter-block sync). v8's regression bundled
// setprio with deferred-PV; this isolates it on the best structure.
// ---------------------------------------------------------------------------
__global__ __launch_bounds__(256, 2) void attn_kernel(const unsigned short* __restrict__ qk,
                                                      const unsigned short* __restrict__ vt,
                                                      unsigned short* __restrict__ O) {
  const int id = blockIdx.x; // 512 blocks
  const int xcd = id & 7;
  const int slot = id >> 3;       // 0..63
  const int qt = slot & 15;       // q-tile within (b,h)
  const int g = slot >> 4;        // 0..3
  const int combo = xcd * 4 + g;  // 0..31
  const int h = combo & 15;
  const int b = combo >> 4;
  const int tid = threadIdx.x;
  const int wave = tid >> 6;
  const int lane = tid & 63;
  const int l31 = lane & 31;
  const int l7 = lane & 7;
  const int hi = lane >> 5;

  __shared__ __align__(16) unsigned short Kt[2][128 * 64];   // [s][d] 32 KB
  __shared__ __align__(16) unsigned short Vt[2][2][64 * 64]; // [half][d][s] 32 KB

  const unsigned short* Qbase = qk + (size_t)b * SEQ * 2048 + h * 64;
  const unsigned short* Kbase = qk + (size_t)b * SEQ * 2048 + 1024 + h * 64;
  const unsigned short* Vbase = vt + ((size_t)b * 1024 + h * 64) * SEQ;

  // staging geometry: one gload16 covers 8 rows x 64 shorts (1 KB), XOR swizzle
  const int rIn = lane >> 3;
  const int gsw = (lane & 7) ^ rIn;

  // Q fragments (B-operand, hoisted): B[n=l31 -> qrow][k=hi*8+e -> d in chunk kc]
  const int qrow = qt * 128 + wave * 32 + l31;
  bf16x8 aq[4];
#pragma unroll
  for (int kc = 0; kc < 4; kc++)
    aq[kc] = *(const bf16x8*)(Qbase + (size_t)qrow * 2048 + kc * 16 + hi * 8);

  f32x16 o_acc[2] = {}; // [dt] O^T: col=l31=qrow, row=(reg&3)+8*(reg>>2)+4*hi -> d
  float lc[4] = {};     // partial denominators (4 chains)

  // prologue: stage tile 0 into buffer 0 (4 K-chunks + 4 V-chunks per wave)
#pragma unroll
  for (int c = 0; c < 4; c++) {
    const int ch = wave * 4 + c; // 0..15
    const int krow = ch * 8 + rIn;
    gload16(Kbase + (size_t)krow * 2048 + gsw * 8, &Kt[0][ch * 512]);
    const int half = ch >> 3, sub = ch & 7;
    const int vrow = sub * 8 + rIn;
    gload16(Vbase + (size_t)vrow * SEQ + half * 64 + gsw * 8, &Vt[0][half][sub * 512]);
  }

#pragma unroll 2
  for (int it = 0; it < SEQ / 128; it++) {
    const int bi = it & 1;
    __syncthreads(); // waits cur-buffer loads (vmcnt) + prev iter readers done
    if (it + 1 < SEQ / 128) {
#pragma unroll
      for (int c = 0; c < 4; c++) {
        const int ch = wave * 4 + c;
        const int krow = ch * 8 + rIn;
        gload16(Kbase + (size_t)((it + 1) * 128 + krow) * 2048 + gsw * 8,
                &Kt[bi ^ 1][ch * 512]);
        const int half = ch >> 3, sub = ch & 7;
        const int vrow = sub * 8 + rIn;
        gload16(Vbase + (size_t)vrow * SEQ + (it + 1) * 128 + half * 64 + gsw * 8,
                &Vt[bi ^ 1][half][sub * 512]);
      }
    }

    unsigned int w[4][8]; // [mt][gi]: P words for s = 32*mt + pattern

    // ---- pass A: mt 0,1 -> QK, softmax ----
    {
      f32x16 sa = {}, sb = {};
      __builtin_amdgcn_s_setprio(1);
#pragma unroll
      for (int kc = 0; kc < 4; kc++) {
        const bf16x8 kf0 = *(const bf16x8*)&Kt[bi][(l31)*64 + ((kc * 16 + hi * 8) ^ (l7 * 8))];
        const bf16x8 kf1 =
            *(const bf16x8*)&Kt[bi][(32 + l31) * 64 + ((kc * 16 + hi * 8) ^ (l7 * 8))];
        sa = __builtin_amdgcn_mfma_f32_32x32x16_bf16(kf0, aq[kc], sa, 0, 0, 0);
        sb = __builtin_amdgcn_mfma_f32_32x32x16_bf16(kf1, aq[kc], sb, 0, 0, 0);
      }
      __builtin_amdgcn_s_setprio(0);
      {
        float p[16];
#pragma unroll
        for (int r2 = 0; r2 < 16; r2++) p[r2] = fast_exp2(sa[r2]);
        lc[0] += ((p[0] + p[1]) + (p[2] + p[3])) + ((p[8] + p[9]) + (p[10] + p[11]));
        lc[1] += ((p[4] + p[5]) + (p[6] + p[7])) + ((p[12] + p[13]) + (p[14] + p[15]));
#pragma unroll
        for (int gi = 0; gi < 8; gi++) w[0][gi] = pkbf(p[2 * gi], p[2 * gi + 1]);
      }
      {
        float p[16];
#pragma unroll
        for (int r2 = 0; r2 < 16; r2++) p[r2] = fast_exp2(sb[r2]);
        lc[2] += ((p[0] + p[1]) + (p[2] + p[3])) + ((p[8] + p[9]) + (p[10] + p[11]));
        lc[3] += ((p[4] + p[5]) + (p[6] + p[7])) + ((p[12] + p[13]) + (p[14] + p[15]));
#pragma unroll
        for (int gi = 0; gi < 8; gi++) w[1][gi] = pkbf(p[2 * gi], p[2 * gi + 1]);
      }
    }

    // ---- pass B: mt 2,3 -> QK, softmax ----
    {
      f32x16 sa = {}, sb = {};
      __builtin_amdgcn_s_setprio(1);
#pragma unroll
      for (int kc = 0; kc < 4; kc++) {
        const bf16x8 kf0 =
            *(const bf16x8*)&Kt[bi][(64 + l31) * 64 + ((kc * 16 + hi * 8) ^ (l7 * 8))];
        const bf16x8 kf1 =
            *(const bf16x8*)&Kt[bi][(96 + l31) * 64 + ((kc * 16 + hi * 8) ^ (l7 * 8))];
        sa = __builtin_amdgcn_mfma_f32_32x32x16_bf16(kf0, aq[kc], sa, 0, 0, 0);
        sb = __builtin_amdgcn_mfma_f32_32x32x16_bf16(kf1, aq[kc], sb, 0, 0, 0);
      }
      __builtin_amdgcn_s_setprio(0);
      {
        float p[16];
#pragma unroll
        for (int r2 = 0; r2 < 16; r2++) p[r2] = fast_exp2(sa[r2]);
        lc[0] += ((p[0] + p[1]) + (p[2] + p[3])) + ((p[8] + p[9]) + (p[10] + p[11]));
        lc[1] += ((p[4] + p[5]) + (p[6] + p[7])) + ((p[12] + p[13]) + (p[14] + p[15]));
#pragma unroll
        for (int gi = 0; gi < 8; gi++) w[2][gi] = pkbf(p[2 * gi], p[2 * gi + 1]);
      }
      {
        float p[16];
#pragma unroll
        for (int r2 = 0; r2 < 16; r2++) p[r2] = fast_exp2(sb[r2]);
        lc[2] += ((p[0] + p[1]) + (p[2] + p[3])) + ((p[8] + p[9]) + (p[10] + p[11]));
        lc[3] += ((p[4] + p[5]) + (p[6] + p[7])) + ((p[12] + p[13]) + (p[14] + p[15]));
#pragma unroll
        for (int gi = 0; gi < 8; gi++) w[3][gi] = pkbf(p[2 * gi], p[2 * gi + 1]);
      }
    }

    // ---- PV: O^T += V^T (A) @ P^T (B), 8 s-chunks ----
#pragma unroll
    for (int sc = 0; sc < 8; sc++) {
      const int n0i = 2 * sc, n1i = 2 * sc + 1;
      const int mt0 = n0i >> 2, b0 = n0i & 3;
      const int mt1 = n1i >> 2, b1 = n1i & 3;
      const auto rA = __builtin_amdgcn_permlane32_swap(w[mt0][2 * b0], w[mt1][2 * b1],
                                                       false, false);
      const auto rB = __builtin_amdgcn_permlane32_swap(w[mt0][2 * b0 + 1], w[mt1][2 * b1 + 1],
                                                       false, false);
      union { unsigned int u[4]; bf16x8 v; } pb;
      pb.u[0] = rA[0]; // k = sc*16+hi*8 + {0,1}
      pb.u[1] = rB[0]; // + {2,3}
      pb.u[2] = rA[1]; // + {4,5}
      pb.u[3] = rB[1]; // + {6,7}
      const int half = sc >> 2, sch = sc & 3;
      const bf16x8 vf0 = *(const bf16x8*)&Vt[bi][half][(l31)*64 +
                                                      ((sch * 16 + hi * 8) ^ (l7 * 8))];
      const bf16x8 vf1 = *(const bf16x8*)&Vt[bi][half][(32 + l31) * 64 +
                                                       ((sch * 16 + hi * 8) ^ (l7 * 8))];
      __builtin_amdgcn_s_setprio(1);
      o_acc[0] = __builtin_amdgcn_mfma_f32_32x32x16_bf16(vf0, pb.v, o_acc[0], 0, 0, 0);
      o_acc[1] = __builtin_amdgcn_mfma_f32_32x32x16_bf16(vf1, pb.v, o_acc[1], 0, 0, 0);
      __builtin_amdgcn_s_setprio(0);
    }
  }

  // epilogue: lanes l and l|32 hold complementary s-subsets of the same qrow
  float lsum = (lc[0] + lc[1]) + (lc[2] + lc[3]);
  const float l_i = lsum + __shfl_xor(lsum, 32, 64);
  const float inv = 1.0f / l_i;
  unsigned short* orow = O + ((size_t)(b * SEQ + qrow)) * H + h * 64;
#pragma unroll
  for (int dt = 0; dt < 2; dt++)
#pragma unroll
    for (int rg = 0; rg < 4; rg++) {
      uint2 d;
      d.x = pkbf(o_acc[dt][4 * rg + 0] * inv, o_acc[dt][4 * rg + 1] * inv);
      d.y = pkbf(o_acc[dt][4 * rg + 2] * inv, o_acc[dt][4 * rg + 3] * inv);
      *(uint2*)&orow[dt * 32 + 8 * rg + 4 * hi] = d;
    }
}

// ---------------------------------------------------------------------------
extern "C" void kernel_launch(void* const* d_in, const int* in_sizes, int n_in,
                              void* d_out, int out_size, void* d_ws, size_t ws_size,
                              hipStream_t stream) {
  const float* x = (const float*)d_in[0];
  const float* Wq = (const float*)d_in[1];
  const float* Wk = (const float*)d_in[2];
  const float* Wv = (const float*)d_in[3];
  const float* Wo = (const float*)d_in[4];
  const float* bo = (const float*)d_in[5];
  const float* gamma = (const float*)d_in[6];
  const float* beta = (const float*)d_in[7];
  float* out = (float*)d_out;

  unsigned short* ws = (unsigned short*)d_ws;
  unsigned short* xn = ws;                              // 4096*1024
  unsigned short* wcat = xn + (size_t)M_TOT * H;        // 4*1024*1024 (Wq,Wk,Wv,Wo)
  unsigned short* wob = wcat + (size_t)3 * H * H;
  unsigned short* qkb = wcat + (size_t)4 * H * H;       // 4096*2048 (Q | K)
  unsigned short* vtb = qkb + (size_t)M_TOT * 2048;     // 2*1024*2048 (V^T)
  unsigned short* atb = vtb + (size_t)BATCH * H * SEQ;  // 4096*1024

  ln_cast_kernel<<<M_TOT + 4096, 256, 0, stream>>>(x, gamma, beta, xn, Wq, Wk, Wv, Wo,
                                                   wcat);
  // QKV: 32 M-blocks x 24 N-blocks, XCD-supertiled (3 N-blocks per XCD)
  gemm128p<0, 3><<<(M_TOT / 128) * (NQKV / 128), 256, 0, stream>>>(
      xn, wcat, qkb, vtb, nullptr, nullptr, nullptr);
  // attn: 512 blocks (128-row q-tiles), XCD-supertiled (4 (b,h) combos per XCD)
  attn_kernel<<<(SEQ / 128) * NHEAD * BATCH, 256, 0, stream>>>(qkb, vtb, atb);
  // proj: 64 M-blocks x 8 N-blocks = 512 blocks (2 blocks/CU)
  proj64p<<<(M_TOT / 64) * (H / 128), 256, 0, stream>>>(atb, wob, bo, x, out);
}

// Round 12
// 183.782 us; speedup vs baseline: 1.0173x; 1.0157x over previous
//
#include <hip/hip_runtime.h>
#include <hip/hip_bf16.h>

// Problem constants
#define H 1024
#define NHEAD 16
#define HDIM 64
#define SEQ 2048
#define BATCH 2
#define M_TOT (BATCH * SEQ) // 4096 tokens
#define NQKV 3072           // fused QKV output cols

typedef __attribute__((ext_vector_type(8))) short bf16x8;  // 8 bf16 = 4 VGPRs (MFMA A/B frag)
typedef __attribute__((ext_vector_type(4))) float f32x4;   // 16x16 MFMA C/D frag
typedef __attribute__((ext_vector_type(16))) float f32x16; // 32x32 MFMA C/D frag

// (1/sqrt(HDIM)) * log2(e), folded into Q at the QKV-GEMM epilogue
#define C2_SCALE 0.18033688f

__device__ __forceinline__ unsigned short f2bf(float f) {
  union { float f; unsigned int u; } a;
  a.f = f;
  unsigned int u = a.u;
  return (unsigned short)((u + 0x7fffu + ((u >> 16) & 1u)) >> 16); // RNE
}

// packed f32x2 -> bf16x2 (v_cvt_pk_bf16_f32), low short = first arg
__device__ __forceinline__ unsigned int pkbf(float a, float b) {
  union { __hip_bfloat162 h; unsigned int u; } cv;
  cv.h = __float22bfloat162_rn(float2{a, b});
  return cv.u;
}

__device__ __forceinline__ float fast_exp2(float x) {
#if defined(__has_builtin) && __has_builtin(__builtin_amdgcn_exp2f)
  return __builtin_amdgcn_exp2f(x);
#else
  return exp2f(x);
#endif
}

// async global->LDS, 16B per lane. LDS dest is wave-uniform base + lane*16.
typedef const __attribute__((address_space(1))) void* gas1_t;
typedef __attribute__((address_space(3))) void* las3_t;
__device__ __forceinline__ void gload16(const void* g, void* l) {
  __builtin_amdgcn_global_load_lds((gas1_t)(unsigned long long)g,
                                   (las3_t)(unsigned int)(unsigned long long)l,
                                   16, 0, 0);
}

// ---------------------------------------------------------------------------
// Kernel 1 (fused): LayerNorm rows (blocks 0..4095) + weight bf16 cast
// (blocks 4096..8191).
// ---------------------------------------------------------------------------
__global__ __launch_bounds__(256) void ln_cast_kernel(const float* __restrict__ x,
                                                      const float* __restrict__ gamma,
                                                      const float* __restrict__ beta,
                                                      unsigned short* __restrict__ xn,
                                                      const float* __restrict__ w0,
                                                      const float* __restrict__ w1,
                                                      const float* __restrict__ w2,
                                                      const float* __restrict__ w3,
                                                      unsigned short* __restrict__ wdst) {
  const int t = threadIdx.x;
  if (blockIdx.x >= M_TOT) {
    const int cb = blockIdx.x - M_TOT;   // 0..4095
    const int y = cb >> 10;              // matrix index 0..3
    const float* s = (y == 0) ? w0 : (y == 1) ? w1 : (y == 2) ? w2 : w3;
    const int i = (cb & 1023) * 256 + t; // float4 index within matrix
    const float4 v = ((const float4*)s)[i];
    ushort4 o;
    o.x = f2bf(v.x);
    o.y = f2bf(v.y);
    o.z = f2bf(v.z);
    o.w = f2bf(v.w);
    ((ushort4*)(wdst + (size_t)y * H * H))[i] = o;
    return;
  }
  const int row = blockIdx.x;
  const float* xr = x + (size_t)row * H;
  float4 v = ((const float4*)xr)[t];
  float s = v.x + v.y + v.z + v.w;
  float s2 = v.x * v.x + v.y * v.y + v.z * v.z + v.w * v.w;
#pragma unroll
  for (int o = 32; o; o >>= 1) {
    s += __shfl_xor(s, o, 64);
    s2 += __shfl_xor(s2, o, 64);
  }
  __shared__ float red[8];
  const int wave = t >> 6;
  if ((t & 63) == 0) {
    red[wave] = s;
    red[wave + 4] = s2;
  }
  __syncthreads();
  const float ts = red[0] + red[1] + red[2] + red[3];
  const float ts2 = red[4] + red[5] + red[6] + red[7];
  const float mu = ts * (1.0f / (float)H);
  const float var = ts2 * (1.0f / (float)H) - mu * mu;
  const float rstd = rsqrtf(var + 1e-5f);
  const float4 g = ((const float4*)gamma)[t];
  const float4 b = ((const float4*)beta)[t];
  ushort4 o;
  o.x = f2bf((v.x - mu) * rstd * g.x + b.x);
  o.y = f2bf((v.y - mu) * rstd * g.y + b.y);
  o.z = f2bf((v.z - mu) * rstd * g.z + b.z);
  o.w = f2bf((v.w - mu) * rstd * g.w + b.w);
  ((ushort4*)(xn + (size_t)row * H))[t] = o;
}

// ---------------------------------------------------------------------------
// QKV GEMM (best measured): 128x128x(BK=32), THREE LDS buffers with a
// 2-tiles-ahead counted-vmcnt pipeline (T4): per iter s_waitcnt vmcnt(4) ->
// raw s_barrier (no drain) -> stage tile it+2 -> ds_read + MFMA.
// LDS 48 KB -> 3 blocks/CU. XCD-supertiled grid (NPX=3). Scalar epilogue.
// ---------------------------------------------------------------------------
template <int EPI, int NPX>
__global__ __launch_bounds__(256, 3) void gemm128p(const unsigned short* __restrict__ A,
                                                   const unsigned short* __restrict__ W,
                                                   unsigned short* __restrict__ qk,
                                                   unsigned short* __restrict__ vt,
                                                   const float* __restrict__ bo,
                                                   const float* __restrict__ x,
                                                   float* __restrict__ out) {
  const int id = blockIdx.x;
  const int xcd = id & 7;
  const int r = id >> 3;
  const int nb = xcd * NPX + (r % NPX);
  const int mb = r / NPX;
  const int m0 = mb * 128;
  const int n0 = nb * 128;
  const int tid = threadIdx.x;
  const int wave = tid >> 6;
  const int lane = tid & 63;
  const int l16 = lane & 15;
  const int quad = lane >> 4;
  const int wx = wave & 1, wy = wave >> 1;

  __shared__ __align__(16) unsigned short As[3][128 * 32];
  __shared__ __align__(16) unsigned short Bs[3][128 * 32];

  // staging: wave stages 32 rows (2 gload16 instrs per matrix) = 4 instrs
  const int sub = lane >> 2;       // row within 16-row group
  const int kcol = (lane & 3) * 8; // 4 lanes cover 32 cols
  const unsigned short* ag = A + (size_t)(m0 + wave * 32 + sub) * H + kcol;
  const unsigned short* bg = W + (size_t)(n0 + wave * 32 + sub) * H + kcol;
  const int lofs = wave * 32 * 32;

  f32x4 acc[4][4] = {};

  auto stage = [&](int t, int B) {
    const int k1 = t * 32;
    gload16(ag + k1, &As[B][lofs]);
    gload16(ag + k1 + 16 * H, &As[B][lofs + 16 * 32]);
    gload16(bg + k1, &Bs[B][lofs]);
    gload16(bg + k1 + 16 * H, &Bs[B][lofs + 16 * 32]);
  };
  auto compute = [&](int bi) {
    bf16x8 af[4], bf[4];
#pragma unroll
    for (int t = 0; t < 4; t++) {
      af[t] = *(const bf16x8*)&As[bi][(wy * 64 + t * 16 + l16) * 32 + quad * 8];
      bf[t] = *(const bf16x8*)&Bs[bi][(wx * 64 + t * 16 + l16) * 32 + quad * 8];
    }
#pragma unroll
    for (int i = 0; i < 4; i++)
#pragma unroll
      for (int j = 0; j < 4; j++)
        acc[i][j] = __builtin_amdgcn_mfma_f32_16x16x32_bf16(af[i], bf[j], acc[i][j], 0, 0, 0);
  };

  // prologue: stage tiles 0,1 (8 loads/wave outstanding)
  stage(0, 0);
  stage(1, 1);

  for (int it = 0; it < H / 32 - 1; it++) {
    asm volatile("s_waitcnt vmcnt(4)" ::: "memory"); // tile it landed (own)
    __builtin_amdgcn_s_barrier();                    // all waves' tile it landed
    if (it + 2 < H / 32) stage(it + 2, (it + 2) % 3);
    compute(it % 3);
  }
  // peeled last iteration: drain everything
  asm volatile("s_waitcnt vmcnt(0)" ::: "memory");
  __builtin_amdgcn_s_barrier();
  compute((H / 32 - 1) % 3);

  if (EPI == 0) {
#pragma unroll
    for (int j = 0; j < 4; j++) {
      const int cb = n0 + wx * 64 + j * 16; // wave-uniform tile col base
      if (cb < 2048) {
        const float qs = (cb < 1024) ? C2_SCALE : 1.0f;
#pragma unroll
        for (int i = 0; i < 4; i++) {
          const int row = m0 + wy * 64 + i * 16 + quad * 4;
#pragma unroll
          for (int r2 = 0; r2 < 4; r2++)
            qk[(size_t)(row + r2) * 2048 + cb + l16] = f2bf(acc[i][j][r2] * qs);
        }
      } else {
        const int n = cb + l16 - 2048; // h*64+d
#pragma unroll
        for (int i = 0; i < 4; i++) {
          const int row0 = m0 + wy * 64 + i * 16 + quad * 4;
          const int b = row0 >> 11;
          const int s = row0 & 2047;
          ushort4 p;
          p.x = f2bf(acc[i][j][0]);
          p.y = f2bf(acc[i][j][1]);
          p.z = f2bf(acc[i][j][2]);
          p.w = f2bf(acc[i][j][3]);
          *(ushort4*)&vt[((size_t)b * 1024 + n) * SEQ + s] = p;
        }
      }
    }
  } else {
#pragma unroll
    for (int j = 0; j < 4; j++) {
      const int col = n0 + wx * 64 + j * 16 + l16;
      const float bv = bo[col];
#pragma unroll
      for (int i = 0; i < 4; i++) {
        const int row = m0 + wy * 64 + i * 16 + quad * 4;
#pragma unroll
        for (int r2 = 0; r2 < 4; r2++) {
          const size_t idx = (size_t)(row + r2) * H + col;
          out[idx] = acc[i][j][r2] + bv + x[idx];
        }
      }
    }
  }
}

// ---------------------------------------------------------------------------
// Proj GEMM (best measured): 64x128x(BK=32), 3-buffer counted-vmcnt
// pipeline (3 loads/stage -> vmcnt(3)). LDS 36 KB. Grid 512 = 2 blocks/CU.
// Scalar epilogue. id&7 = N-block (== XCD).
// ---------------------------------------------------------------------------
__global__ __launch_bounds__(256, 4) void proj64p(const unsigned short* __restrict__ A,
                                                  const unsigned short* __restrict__ W,
                                                  const float* __restrict__ bo,
                                                  const float* __restrict__ x,
                                                  float* __restrict__ out) {
  const int id = blockIdx.x; // 512 blocks
  const int nb = id & 7;     // N-block = XCD
  const int mb = id >> 3;    // 0..63
  const int m0 = mb * 64;
  const int n0 = nb * 128;
  const int tid = threadIdx.x;
  const int wave = tid >> 6;
  const int lane = tid & 63;
  const int l16 = lane & 15;
  const int quad = lane >> 4;
  const int wx = wave & 1, wy = wave >> 1;

  __shared__ __align__(16) unsigned short As[3][64 * 32];
  __shared__ __align__(16) unsigned short Bs[3][128 * 32];

  // staging: wave stages 16 A-rows (1 gload16) + 32 B-rows (2 gload16)
  const int sub = lane >> 2;       // row within 16-row group
  const int kcol = (lane & 3) * 8; // 4 lanes cover 32 cols
  const unsigned short* ag = A + (size_t)(m0 + wave * 16 + sub) * H + kcol;
  const unsigned short* bg = W + (size_t)(n0 + wave * 32 + sub) * H + kcol;
  const int lofsA = wave * 16 * 32;
  const int lofsB = wave * 32 * 32;

  f32x4 acc[2][4] = {};

  auto stage = [&](int t, int B) {
    const int k1 = t * 32;
    gload16(ag + k1, &As[B][lofsA]);
    gload16(bg + k1, &Bs[B][lofsB]);
    gload16(bg + k1 + 16 * H, &Bs[B][lofsB + 16 * 32]);
  };
  auto compute = [&](int bi) {
    bf16x8 af[2], bf[4];
#pragma unroll
    for (int t = 0; t < 2; t++)
      af[t] = *(const bf16x8*)&As[bi][(wy * 32 + t * 16 + l16) * 32 + quad * 8];
#pragma unroll
    for (int t = 0; t < 4; t++)
      bf[t] = *(const bf16x8*)&Bs[bi][(wx * 64 + t * 16 + l16) * 32 + quad * 8];
#pragma unroll
    for (int i = 0; i < 2; i++)
#pragma unroll
      for (int j = 0; j < 4; j++)
        acc[i][j] = __builtin_amdgcn_mfma_f32_16x16x32_bf16(af[i], bf[j], acc[i][j], 0, 0, 0);
  };

  stage(0, 0);
  stage(1, 1); // 6 loads/wave outstanding

  for (int it = 0; it < H / 32 - 1; it++) {
    asm volatile("s_waitcnt vmcnt(3)" ::: "memory"); // tile it landed (own)
    __builtin_amdgcn_s_barrier();
    if (it + 2 < H / 32) stage(it + 2, (it + 2) % 3);
    compute(it % 3);
  }
  asm volatile("s_waitcnt vmcnt(0)" ::: "memory");
  __builtin_amdgcn_s_barrier();
  compute((H / 32 - 1) % 3);

#pragma unroll
  for (int j = 0; j < 4; j++) {
    const int col = n0 + wx * 64 + j * 16 + l16;
    const float bv = bo[col];
#pragma unroll
    for (int i = 0; i < 2; i++) {
      const int row = m0 + wy * 32 + i * 16 + quad * 4;
#pragma unroll
      for (int r2 = 0; r2 < 4; r2++) {
        const size_t idx = (size_t)(row + r2) * H + col;
        out[idx] = acc[i][j][r2] + bv + x[idx];
      }
    }
  }
}

// ---------------------------------------------------------------------------
// Flash attention v10 (best measured: 46.9 us): 32x32x16 in-register-P
// (cvt_pk + permlane32_swap), KVBLK=128, 16 iters, LDS 64 KB, 512 blocks,
// XCD-supertiled. No setprio (v13 isolated it: neutral-to-negative — the
// 4 waves/block are barrier-lockstep, the m190 null regime).
// ---------------------------------------------------------------------------
__global__ __launch_bounds__(256, 2) void attn_kernel(const unsigned short* __restrict__ qk,
                                                      const unsigned short* __restrict__ vt,
                                                      unsigned short* __restrict__ O) {
  const int id = blockIdx.x; // 512 blocks
  const int xcd = id & 7;
  const int slot = id >> 3;       // 0..63
  const int qt = slot & 15;       // q-tile within (b,h)
  const int g = slot >> 4;        // 0..3
  const int combo = xcd * 4 + g;  // 0..31
  const int h = combo & 15;
  const int b = combo >> 4;
  const int tid = threadIdx.x;
  const int wave = tid >> 6;
  const int lane = tid & 63;
  const int l31 = lane & 31;
  const int l7 = lane & 7;
  const int hi = lane >> 5;

  __shared__ __align__(16) unsigned short Kt[2][128 * 64];   // [s][d] 32 KB
  __shared__ __align__(16) unsigned short Vt[2][2][64 * 64]; // [half][d][s] 32 KB

  const unsigned short* Qbase = qk + (size_t)b * SEQ * 2048 + h * 64;
  const unsigned short* Kbase = qk + (size_t)b * SEQ * 2048 + 1024 + h * 64;
  const unsigned short* Vbase = vt + ((size_t)b * 1024 + h * 64) * SEQ;

  // staging geometry: one gload16 covers 8 rows x 64 shorts (1 KB), XOR swizzle
  const int rIn = lane >> 3;
  const int gsw = (lane & 7) ^ rIn;

  // Q fragments (B-operand, hoisted): B[n=l31 -> qrow][k=hi*8+e -> d in chunk kc]
  const int qrow = qt * 128 + wave * 32 + l31;
  bf16x8 aq[4];
#pragma unroll
  for (int kc = 0; kc < 4; kc++)
    aq[kc] = *(const bf16x8*)(Qbase + (size_t)qrow * 2048 + kc * 16 + hi * 8);

  f32x16 o_acc[2] = {}; // [dt] O^T: col=l31=qrow, row=(reg&3)+8*(reg>>2)+4*hi -> d
  float lc[4] = {};     // partial denominators (4 chains)

  // prologue: stage tile 0 into buffer 0 (4 K-chunks + 4 V-chunks per wave)
#pragma unroll
  for (int c = 0; c < 4; c++) {
    const int ch = wave * 4 + c; // 0..15
    const int krow = ch * 8 + rIn;
    gload16(Kbase + (size_t)krow * 2048 + gsw * 8, &Kt[0][ch * 512]);
    const int half = ch >> 3, sub = ch & 7;
    const int vrow = sub * 8 + rIn;
    gload16(Vbase + (size_t)vrow * SEQ + half * 64 + gsw * 8, &Vt[0][half][sub * 512]);
  }

#pragma unroll 2
  for (int it = 0; it < SEQ / 128; it++) {
    const int bi = it & 1;
    __syncthreads(); // waits cur-buffer loads (vmcnt) + prev iter readers done
    if (it + 1 < SEQ / 128) {
#pragma unroll
      for (int c = 0; c < 4; c++) {
        const int ch = wave * 4 + c;
        const int krow = ch * 8 + rIn;
        gload16(Kbase + (size_t)((it + 1) * 128 + krow) * 2048 + gsw * 8,
                &Kt[bi ^ 1][ch * 512]);
        const int half = ch >> 3, sub = ch & 7;
        const int vrow = sub * 8 + rIn;
        gload16(Vbase + (size_t)vrow * SEQ + (it + 1) * 128 + half * 64 + gsw * 8,
                &Vt[bi ^ 1][half][sub * 512]);
      }
    }

    unsigned int w[4][8]; // [mt][gi]: P words for s = 32*mt + pattern

    // ---- pass A: mt 0,1 -> QK, softmax ----
    {
      f32x16 sa = {}, sb = {};
#pragma unroll
      for (int kc = 0; kc < 4; kc++) {
        const bf16x8 kf0 = *(const bf16x8*)&Kt[bi][(l31)*64 + ((kc * 16 + hi * 8) ^ (l7 * 8))];
        const bf16x8 kf1 =
            *(const bf16x8*)&Kt[bi][(32 + l31) * 64 + ((kc * 16 + hi * 8) ^ (l7 * 8))];
        sa = __builtin_amdgcn_mfma_f32_32x32x16_bf16(kf0, aq[kc], sa, 0, 0, 0);
        sb = __builtin_amdgcn_mfma_f32_32x32x16_bf16(kf1, aq[kc], sb, 0, 0, 0);
      }
      {
        float p[16];
#pragma unroll
        for (int r2 = 0; r2 < 16; r2++) p[r2] = fast_exp2(sa[r2]);
        lc[0] += ((p[0] + p[1]) + (p[2] + p[3])) + ((p[8] + p[9]) + (p[10] + p[11]));
        lc[1] += ((p[4] + p[5]) + (p[6] + p[7])) + ((p[12] + p[13]) + (p[14] + p[15]));
#pragma unroll
        for (int gi = 0; gi < 8; gi++) w[0][gi] = pkbf(p[2 * gi], p[2 * gi + 1]);
      }
      {
        float p[16];
#pragma unroll
        for (int r2 = 0; r2 < 16; r2++) p[r2] = fast_exp2(sb[r2]);
        lc[2] += ((p[0] + p[1]) + (p[2] + p[3])) + ((p[8] + p[9]) + (p[10] + p[11]));
        lc[3] += ((p[4] + p[5]) + (p[6] + p[7])) + ((p[12] + p[13]) + (p[14] + p[15]));
#pragma unroll
        for (int gi = 0; gi < 8; gi++) w[1][gi] = pkbf(p[2 * gi], p[2 * gi + 1]);
      }
    }

    // ---- pass B: mt 2,3 -> QK, softmax ----
    {
      f32x16 sa = {}, sb = {};
#pragma unroll
      for (int kc = 0; kc < 4; kc++) {
        const bf16x8 kf0 =
            *(const bf16x8*)&Kt[bi][(64 + l31) * 64 + ((kc * 16 + hi * 8) ^ (l7 * 8))];
        const bf16x8 kf1 =
            *(const bf16x8*)&Kt[bi][(96 + l31) * 64 + ((kc * 16 + hi * 8) ^ (l7 * 8))];
        sa = __builtin_amdgcn_mfma_f32_32x32x16_bf16(kf0, aq[kc], sa, 0, 0, 0);
        sb = __builtin_amdgcn_mfma_f32_32x32x16_bf16(kf1, aq[kc], sb, 0, 0, 0);
      }
      {
        float p[16];
#pragma unroll
        for (int r2 = 0; r2 < 16; r2++) p[r2] = fast_exp2(sa[r2]);
        lc[0] += ((p[0] + p[1]) + (p[2] + p[3])) + ((p[8] + p[9]) + (p[10] + p[11]));
        lc[1] += ((p[4] + p[5]) + (p[6] + p[7])) + ((p[12] + p[13]) + (p[14] + p[15]));
#pragma unroll
        for (int gi = 0; gi < 8; gi++) w[2][gi] = pkbf(p[2 * gi], p[2 * gi + 1]);
      }
      {
        float p[16];
#pragma unroll
        for (int r2 = 0; r2 < 16; r2++) p[r2] = fast_exp2(sb[r2]);
        lc[2] += ((p[0] + p[1]) + (p[2] + p[3])) + ((p[8] + p[9]) + (p[10] + p[11]));
        lc[3] += ((p[4] + p[5]) + (p[6] + p[7])) + ((p[12] + p[13]) + (p[14] + p[15]));
#pragma unroll
        for (int gi = 0; gi < 8; gi++) w[3][gi] = pkbf(p[2 * gi], p[2 * gi + 1]);
      }
    }

    // ---- PV: O^T += V^T (A) @ P^T (B), 8 s-chunks ----
#pragma unroll
    for (int sc = 0; sc < 8; sc++) {
      const int n0i = 2 * sc, n1i = 2 * sc + 1;
      const int mt0 = n0i >> 2, b0 = n0i & 3;
      const int mt1 = n1i >> 2, b1 = n1i & 3;
      const auto rA = __builtin_amdgcn_permlane32_swap(w[mt0][2 * b0], w[mt1][2 * b1],
                                                       false, false);
      const auto rB = __builtin_amdgcn_permlane32_swap(w[mt0][2 * b0 + 1], w[mt1][2 * b1 + 1],
                                                       false, false);
      union { unsigned int u[4]; bf16x8 v; } pb;
      pb.u[0] = rA[0]; // k = sc*16+hi*8 + {0,1}
      pb.u[1] = rB[0]; // + {2,3}
      pb.u[2] = rA[1]; // + {4,5}
      pb.u[3] = rB[1]; // + {6,7}
      const int half = sc >> 2, sch = sc & 3;
#pragma unroll
      for (int dt = 0; dt < 2; dt++) {
        const bf16x8 vf = *(const bf16x8*)&Vt[bi][half][(dt * 32 + l31) * 64 +
                                                       ((sch * 16 + hi * 8) ^ (l7 * 8))];
        o_acc[dt] = __builtin_amdgcn_mfma_f32_32x32x16_bf16(vf, pb.v, o_acc[dt], 0, 0, 0);
      }
    }
  }

  // epilogue: lanes l and l|32 hold complementary s-subsets of the same qrow
  float lsum = (lc[0] + lc[1]) + (lc[2] + lc[3]);
  const float l_i = lsum + __shfl_xor(lsum, 32, 64);
  const float inv = 1.0f / l_i;
  unsigned short* orow = O + ((size_t)(b * SEQ + qrow)) * H + h * 64;
#pragma unroll
  for (int dt = 0; dt < 2; dt++)
#pragma unroll
    for (int rg = 0; rg < 4; rg++) {
      uint2 d;
      d.x = pkbf(o_acc[dt][4 * rg + 0] * inv, o_acc[dt][4 * rg + 1] * inv);
      d.y = pkbf(o_acc[dt][4 * rg + 2] * inv, o_acc[dt][4 * rg + 3] * inv);
      *(uint2*)&orow[dt * 32 + 8 * rg + 4 * hi] = d;
    }
}

// ---------------------------------------------------------------------------
extern "C" void kernel_launch(void* const* d_in, const int* in_sizes, int n_in,
                              void* d_out, int out_size, void* d_ws, size_t ws_size,
                              hipStream_t stream) {
  const float* x = (const float*)d_in[0];
  const float* Wq = (const float*)d_in[1];
  const float* Wk = (const float*)d_in[2];
  const float* Wv = (const float*)d_in[3];
  const float* Wo = (const float*)d_in[4];
  const float* bo = (const float*)d_in[5];
  const float* gamma = (const float*)d_in[6];
  const float* beta = (const float*)d_in[7];
  float* out = (float*)d_out;

  unsigned short* ws = (unsigned short*)d_ws;
  unsigned short* xn = ws;                              // 4096*1024
  unsigned short* wcat = xn + (size_t)M_TOT * H;        // 4*1024*1024 (Wq,Wk,Wv,Wo)
  unsigned short* wob = wcat + (size_t)3 * H * H;
  unsigned short* qkb = wcat + (size_t)4 * H * H;       // 4096*2048 (Q | K)
  unsigned short* vtb = qkb + (size_t)M_TOT * 2048;     // 2*1024*2048 (V^T)
  unsigned short* atb = vtb + (size_t)BATCH * H * SEQ;  // 4096*1024

  ln_cast_kernel<<<M_TOT + 4096, 256, 0, stream>>>(x, gamma, beta, xn, Wq, Wk, Wv, Wo,
                                                   wcat);
  // QKV: 32 M-blocks x 24 N-blocks, XCD-supertiled (3 N-blocks per XCD)
  gemm128p<0, 3><<<(M_TOT / 128) * (NQKV / 128), 256, 0, stream>>>(
      xn, wcat, qkb, vtb, nullptr, nullptr, nullptr);
  // attn: 512 blocks (128-row q-tiles), XCD-supertiled (4 (b,h) combos per XCD)
  attn_kernel<<<(SEQ / 128) * NHEAD * BATCH, 256, 0, stream>>>(qkb, vtb, atb);
  // proj: 64 M-blocks x 8 N-blocks = 512 blocks (2 blocks/CU)
  proj64p<<<(M_TOT / 64) * (H / 128), 256, 0, stream>>>(atb, wob, bo, x, out);
}